// Round 11
// baseline (360.643 us; speedup 1.0000x reference)
//
#include <hip/hip_runtime.h>
#include <hip/hip_bf16.h>
#include <cstdint>

#define N_NODES 50000
#define N_EDGES 800000
#define D 128
#define NBUCK 196          // ceil(50000 / 256), bucket = dst >> 8
#define CAP 4608           // per-bucket capacity; mean 4096, sigma 64 -> 8 sigma slack

typedef __attribute__((ext_vector_type(4))) float f32x4;
typedef __attribute__((ext_vector_type(8))) short s16x8;

__device__ __forceinline__ float bflo(uint32_t v) { return __uint_as_float(v << 16); }
__device__ __forceinline__ float bfhi(uint32_t v) { return __uint_as_float(v & 0xffff0000u); }
__device__ __forceinline__ uint32_t f2b(float f) {
    uint32_t x = __float_as_uint(f);
    uint32_t r = x + 0x7fffu + ((x >> 16) & 1u);   // RNE to bf16
    return r >> 16;
}
__device__ __forceinline__ uint32_t pack2(float lo, float hi) {
    return f2b(lo) | (f2b(hi) << 16);
}

// ---------------- packed: prep (x->bf16, weights->bf16) + edge bucketing ---
__global__ __launch_bounds__(256) void pb_k(const float* __restrict__ x,
                       const float* __restrict__ Wl0, const float* __restrict__ Wr0,
                       const float* __restrict__ Wl1, const float* __restrict__ Wr1,
                       const float* __restrict__ Wl2, const float* __restrict__ Wr2,
                       uint32_t* __restrict__ X0, uint32_t* __restrict__ Wc,
                       const int* __restrict__ src, const int* __restrict__ dst,
                       int* __restrict__ bcnt, uint2* __restrict__ ebuf)
{
    const int t = threadIdx.x;
    if (blockIdx.x < 512) {
        __shared__ int h[256], base[256], cur[256];
        h[t] = 0; cur[t] = 0;
        __syncthreads();
        const int chunk = (N_EDGES + 511) / 512;
        const int e0 = blockIdx.x * chunk;
        int e1 = e0 + chunk; if (e1 > N_EDGES) e1 = N_EDGES;
        for (int e = e0 + t; e < e1; e += 256) {
            int b = dst[e] >> 8;
            atomicAdd(&h[b], 1);
        }
        __syncthreads();
        if (t < NBUCK) base[t] = (h[t] > 0) ? atomicAdd(&bcnt[t], h[t]) : 0;
        __syncthreads();
        for (int e = e0 + t; e < e1; e += 256) {
            int s = src[e], d = dst[e];
            int b = d >> 8;
            int r = atomicAdd(&cur[b], 1);
            int pos = base[b] + r;
            if (pos < CAP) ebuf[b * CAP + pos] = make_uint2((uint32_t)s, (uint32_t)d);
        }
    } else {
        const int NX = N_NODES * D / 2;      // 3,200,000 uints
        const int NW = 3 * 128 * 128;        // 49,152 uints
        const int bid = blockIdx.x - 512;    // 0..2047
        for (int i = bid * 256 + t; i < NX + NW; i += 2048 * 256) {
            if (i < NX) {
                const float2 v = reinterpret_cast<const float2*>(x)[i];
                X0[i] = pack2(v.x, v.y);
            } else {
                int j = i - NX;
                int l = j / 16384;
                int r = j % 16384;
                int n = r >> 7;
                int k2 = (r & 127) * 2;
                const float* Wl = (l == 0) ? Wl0 : (l == 1) ? Wl1 : Wl2;
                const float* Wr = (l == 0) ? Wr0 : (l == 1) ? Wr1 : Wr2;
                float a, b;
                if (k2 < 128) { a = Wl[n * 128 + k2];       b = Wl[n * 128 + k2 + 1]; }
                else          { a = Wr[n * 128 + k2 - 128]; b = Wr[n * 128 + k2 - 127]; }
                Wc[j] = pack2(a, b);
            }
        }
    }
}

// ---------------- CSR: one block per bucket, self-scans bucket counts ------
__global__ __launch_bounds__(256) void csr_k(const uint2* __restrict__ ebuf,
                                             const int* __restrict__ bcnt,
                                             int* __restrict__ rowptr,
                                             int* __restrict__ adj)
{
    __shared__ int bs[256], cntL[256], offL[256], curL[256];
    const int b = blockIdx.x;
    const int t = threadIdx.x;
    const int n0 = b << 8;
    int bv = (t < NBUCK) ? bcnt[t] : 0;
    bs[t] = bv;
    __syncthreads();
    for (int d = 1; d < 256; d <<= 1) {
        int tmp = (t >= d) ? bs[t - d] : 0;
        __syncthreads();
        bs[t] += tmp;
        __syncthreads();
    }
    const int gbase = (b == 0) ? 0 : bs[b - 1];
    const int m = bcnt[b];
    cntL[t] = 0; curL[t] = 0;
    __syncthreads();
    const uint2* eb = ebuf + b * CAP;
    for (int i = t; i < m; i += 256)
        atomicAdd(&cntL[(int)eb[i].y - n0], 1);
    __syncthreads();
    int v = cntL[t];
    offL[t] = v;
    __syncthreads();
    for (int d = 1; d < 256; d <<= 1) {
        int tmp = (t >= d) ? offL[t - d] : 0;
        __syncthreads();
        offL[t] += tmp;
        __syncthreads();
    }
    int excl = offL[t] - v;
    int node = n0 + t;
    if (node < N_NODES) rowptr[node] = gbase + excl;
    if (b == NBUCK - 1 && t == 0) rowptr[N_NODES] = N_EDGES;
    __syncthreads();
    offL[t] = excl;
    __syncthreads();
    for (int i = t; i < m; i += 256) {
        uint2 e = eb[i];
        int d = (int)e.y - n0;
        int r = atomicAdd(&curL[d], 1);
        adj[gbase + offL[d] + r] = (int)e.x;
    }
}

// ---------------- fused layer: mean-agg (into LDS) + GEMM -----------------
// Block = 256 thr (4 waves), 64 output rows. Phase 1: wave w aggregates
// nodes [blockBase+w*16, +16) -> bf16 means in XOR-swizzled LDS. Phase 2:
// wave w computes rows [rowBase, +16) x 128 cols, K=256 (means | self),
// B read from global (L1/L2-resident 64 KB).
// LAYER 0: +relu, bf16 out. LAYER 1: bf16 out + BN col-stats -> colsums.
// LAYER 2: BN+relu applied to G2 on the fly (gather + self path); fp32 out.
__device__ __forceinline__ s16x8 bn8(uint4 u, const float* bnS, int cb) {
    uint32_t uu[4] = {u.x, u.y, u.z, u.w};
    uint32_t w[4];
#pragma unroll
    for (int i = 0; i < 4; ++i) {
        int c = cb + 2 * i;
        float lo = fmaxf(fmaf(bflo(uu[i]), bnS[c],     bnS[128 + c]),     0.f);
        float hi = fmaxf(fmaf(bfhi(uu[i]), bnS[c + 1], bnS[128 + c + 1]), 0.f);
        w[i] = pack2(lo, hi);
    }
    uint4 r = make_uint4(w[0], w[1], w[2], w[3]);
    return __builtin_bit_cast(s16x8, r);
}

template <int LAYER>
__global__ __launch_bounds__(256) void fused_k(const uint32_t* __restrict__ inB,
                                               const int* __restrict__ rowptr,
                                               const int* __restrict__ adj,
                                               const uint32_t* __restrict__ Wc,
                                               const float* __restrict__ bias,
                                               void* __restrict__ outp,
                                               float* __restrict__ colsums,
                                               const float* __restrict__ gamma,
                                               const float* __restrict__ beta)
{
    __shared__ uint32_t meanS[4096];   // 64 rows x 128 bf16, XOR-swizzled
    __shared__ float extraS[256];      // L1: col {sum,sumsq}; L2: BN {sc,sh}
    const int t = threadIdx.x;
    const int lane = t & 63;
    const int wid = t >> 6;
    const int blockBase = blockIdx.x * 64;

    if constexpr (LAYER == 1) extraS[t] = 0.f;
    if constexpr (LAYER == 2) {
        if (t < 128) {
            float mu  = colsums[t] * (1.0f / N_NODES);
            float var = colsums[128 + t] * (1.0f / N_NODES) - mu * mu;
            float sc  = gamma[t] * rsqrtf(var + 1e-5f);
            extraS[t] = sc;
            extraS[128 + t] = beta[t] - mu * sc;
        }
    }
    __syncthreads();

    // ---- phase 1: gather means for 16 nodes per wave ----
    const int sub = lane >> 4;     // 0..3
    const int col4 = lane & 15;    // 16B chunk within row
    float vsc[8], vsh[8];
    if constexpr (LAYER == 2) {
#pragma unroll
        for (int k = 0; k < 8; ++k) {
            int c = col4 * 8 + k;
            vsc[k] = extraS[c]; vsh[k] = extraS[128 + c];
        }
    }
    for (int i = 0; i < 16; ++i) {
        const int rl = wid * 16 + i;          // local row
        const int ni = blockBase + rl;
        int start = 0, end = 0;
        if (ni < N_NODES) { start = rowptr[ni]; end = rowptr[ni + 1]; }
        float acc[8];
#pragma unroll
        for (int k = 0; k < 8; ++k) acc[k] = 0.f;
        for (int base = start; base < end; base += 64) {
            int cnt = end - base;
            if (cnt > 64) cnt = 64;
            int idx = (base + lane < end) ? adj[base + lane] : 0;
            for (int j = 0; j < cnt; j += 8) {
                int e0 = j + sub;
                int e1 = j + 4 + sub;
                int s0 = __shfl(idx, e0, 64);
                int s1 = __shfl(idx, e1, 64);
                bool v0 = e0 < cnt;
                bool v1 = e1 < cnt;
                uint4 a = *reinterpret_cast<const uint4*>(inB + (v0 ? s0 : 0) * 64 + col4 * 4);
                uint4 b = *reinterpret_cast<const uint4*>(inB + (v1 ? s1 : 0) * 64 + col4 * 4);
                if constexpr (LAYER == 2) {
                    float m0 = v0 ? 1.f : 0.f;
                    float m1 = v1 ? 1.f : 0.f;
#define ACCBN(K, GA, GB) acc[K] += m0 * fmaxf(fmaf((GA), vsc[K], vsh[K]), 0.f) \
                                 + m1 * fmaxf(fmaf((GB), vsc[K], vsh[K]), 0.f)
                    ACCBN(0, bflo(a.x), bflo(b.x)); ACCBN(1, bfhi(a.x), bfhi(b.x));
                    ACCBN(2, bflo(a.y), bflo(b.y)); ACCBN(3, bfhi(a.y), bfhi(b.y));
                    ACCBN(4, bflo(a.z), bflo(b.z)); ACCBN(5, bfhi(a.z), bfhi(b.z));
                    ACCBN(6, bflo(a.w), bflo(b.w)); ACCBN(7, bfhi(a.w), bfhi(b.w));
#undef ACCBN
                } else {
                    if (!v0) a = make_uint4(0, 0, 0, 0);
                    if (!v1) b = make_uint4(0, 0, 0, 0);
                    acc[0] += bflo(a.x); acc[1] += bfhi(a.x);
                    acc[2] += bflo(a.y); acc[3] += bfhi(a.y);
                    acc[4] += bflo(a.z); acc[5] += bfhi(a.z);
                    acc[6] += bflo(a.w); acc[7] += bfhi(a.w);
                    acc[0] += bflo(b.x); acc[1] += bfhi(b.x);
                    acc[2] += bflo(b.y); acc[3] += bfhi(b.y);
                    acc[4] += bflo(b.z); acc[5] += bfhi(b.z);
                    acc[6] += bflo(b.w); acc[7] += bfhi(b.w);
                }
            }
        }
#pragma unroll
        for (int k = 0; k < 8; ++k) {
            acc[k] += __shfl_xor(acc[k], 16, 64);
            acc[k] += __shfl_xor(acc[k], 32, 64);
        }
        if (sub == 0) {
            int deg = end - start;
            float sc = 1.0f / (float)(deg > 0 ? deg : 1);
            uint4 w;
            w.x = pack2(acc[0] * sc, acc[1] * sc);
            w.y = pack2(acc[2] * sc, acc[3] * sc);
            w.z = pack2(acc[4] * sc, acc[5] * sc);
            w.w = pack2(acc[6] * sc, acc[7] * sc);
            const int off = (col4 * 4) ^ ((rl & 7) << 2);
            *reinterpret_cast<uint4*>(meanS + rl * 64 + off) = w;
        }
    }
    __syncthreads();

    // ---- phase 2: MFMA, 16 rows per wave ----
    const int l15 = lane & 15;
    const int kc = lane >> 4;
    const int rowBase = blockBase + wid * 16;
    const int rl0 = wid * 16 + l15;           // local LDS row for A
    int m0 = rowBase + l15;
    int m0c = m0 < N_NODES ? m0 : N_NODES - 1;
    const uint32_t* Wg = Wc + LAYER * 16384;

    f32x4 acc[8];
#pragma unroll
    for (int b = 0; b < 8; ++b) acc[b] = (f32x4){0.f, 0.f, 0.f, 0.f};

#pragma unroll
    for (int ks = 0; ks < 8; ++ks) {
        const int koff = (ks & 3) * 16 + kc * 4;
        s16x8 a0;
        if (ks < 4) {
            a0 = *reinterpret_cast<const s16x8*>(meanS + rl0 * 64 + (koff ^ ((rl0 & 7) << 2)));
        } else {
            if constexpr (LAYER == 2) {
                const int cb = (ks & 3) * 32 + kc * 8;
                uint4 u0 = *reinterpret_cast<const uint4*>(inB + m0c * 64 + koff);
                a0 = bn8(u0, extraS, cb);
            } else {
                a0 = *reinterpret_cast<const s16x8*>(inB + m0c * 64 + koff);
            }
        }
#pragma unroll
        for (int nf = 0; nf < 8; ++nf) {
            s16x8 b = *reinterpret_cast<const s16x8*>(Wg + (nf * 16 + l15) * 128 + ks * 16 + kc * 4);
            acc[nf] = __builtin_amdgcn_mfma_f32_16x16x32_bf16(a0, b, acc[nf], 0, 0, 0);
        }
    }

    const int rb = rowBase + (lane >> 4) * 4;
#pragma unroll
    for (int nf = 0; nf < 8; ++nf) {
        int col = nf * 16 + l15;
        float bia = bias[col];
        float s = 0.f, q = 0.f;
#pragma unroll
        for (int r = 0; r < 4; ++r) {
            int row = rb + r;
            if (row < N_NODES) {
                float v = acc[nf][r] + bia;
                if (LAYER == 0) v = v > 0.f ? v : 0.f;
                if (LAYER == 2)
                    ((float*)outp)[row * 128 + col] = v;
                else
                    ((unsigned short*)outp)[row * 128 + col] = (unsigned short)f2b(v);
                if constexpr (LAYER == 1) { s += v; q += v * v; }
            }
        }
        if constexpr (LAYER == 1) {
            atomicAdd(&extraS[col], s);
            atomicAdd(&extraS[128 + col], q);
        }
    }
    if constexpr (LAYER == 1) {
        __syncthreads();
        if (t < 128) {
            atomicAdd(&colsums[t], extraS[t]);
            atomicAdd(&colsums[128 + t], extraS[128 + t]);
        }
    }
}

// ---------------- launch ---------------------------------------------------
// Workspace (~49.2 MB):
//   bcnt    @ 0          (784, pad 1024)   [zeroed]
//   colsums @ 1024       (1024)            [zeroed]
//   rowptr  @ 4096       (200,004)
//   adj     @ 204,160    (3,200,000)
//   ebuf    @ 3,404,160  (7,225,344 = 196*4608*8)
//   bufA    @ 10,629,504 (12.8 MB)  X0, later G2
//   bufC    @ 36,229,504 (12.8 MB)  G1
//   Wc      @ 49,029,504 (196,608)
extern "C" void kernel_launch(void* const* d_in, const int* in_sizes, int n_in,
                              void* d_out, int out_size, void* d_ws, size_t ws_size,
                              hipStream_t stream)
{
    const float* x      = (const float*)d_in[0];
    const int*   ei     = (const int*)d_in[1];
    const float* Wl0    = (const float*)d_in[2];
    const float* bl0    = (const float*)d_in[3];
    const float* Wr0    = (const float*)d_in[4];
    const float* Wl1    = (const float*)d_in[5];
    const float* bl1    = (const float*)d_in[6];
    const float* Wr1    = (const float*)d_in[7];
    const float* Wl2    = (const float*)d_in[8];
    const float* bl2    = (const float*)d_in[9];
    const float* Wr2    = (const float*)d_in[10];
    const float* gamma1 = (const float*)d_in[11];
    const float* beta1  = (const float*)d_in[12];

    char* ws = (char*)d_ws;
    int*      bcnt    = (int*)(ws + 0);
    float*    colsums = (float*)(ws + 1024);
    int*      rowptr  = (int*)(ws + 4096);
    int*      adj     = (int*)(ws + 204160);
    uint2*    ebuf    = (uint2*)(ws + 3404160);
    uint32_t* bufA    = (uint32_t*)(ws + 10629504);
    uint32_t* bufC    = (uint32_t*)(ws + 36229504);
    uint32_t* Wc      = (uint32_t*)(ws + 49029504);
    // liveness-based aliases
    uint32_t* X0 = bufA;   // dead after fused<0>
    uint32_t* G1 = bufC;   // dead after fused<1>
    uint32_t* G2 = bufA;

    const int* srcI = ei;
    const int* dstI = ei + N_EDGES;

    hipMemsetAsync(ws, 0, 2048, stream);   // bcnt + colsums
    pb_k<<<2560, 256, 0, stream>>>(x, Wl0, Wr0, Wl1, Wr1, Wl2, Wr2, X0, Wc,
                                   srcI, dstI, bcnt, ebuf);
    csr_k<<<NBUCK, 256, 0, stream>>>(ebuf, bcnt, rowptr, adj);

    const int NBLK = (N_NODES + 63) / 64;   // 782
    fused_k<0><<<NBLK, 256, 0, stream>>>(X0, rowptr, adj, Wc, bl0, (void*)G1,
                                         nullptr, nullptr, nullptr);
    fused_k<1><<<NBLK, 256, 0, stream>>>(G1, rowptr, adj, Wc, bl1, (void*)G2,
                                         colsums, nullptr, nullptr);
    fused_k<2><<<NBLK, 256, 0, stream>>>(G2, rowptr, adj, Wc, bl2, d_out,
                                         colsums, gamma1, beta1);
}

// Round 13
// 345.557 us; speedup vs baseline: 1.0437x; 1.0437x over previous
//
#include <hip/hip_runtime.h>
#include <hip/hip_bf16.h>
#include <cstdint>

#define N_NODES 50000
#define N_EDGES 800000
#define D 128
#define NBUCK 196          // ceil(50000 / 256), bucket = dst >> 8
#define CAP 4608           // per-bucket capacity; mean 4096, sigma 64 -> 8 sigma slack

typedef __attribute__((ext_vector_type(4))) float f32x4;
typedef __attribute__((ext_vector_type(8))) short s16x8;

__device__ __forceinline__ float bflo(uint32_t v) { return __uint_as_float(v << 16); }
__device__ __forceinline__ float bfhi(uint32_t v) { return __uint_as_float(v & 0xffff0000u); }
__device__ __forceinline__ uint32_t f2b(float f) {
    uint32_t x = __float_as_uint(f);
    uint32_t r = x + 0x7fffu + ((x >> 16) & 1u);   // RNE to bf16
    return r >> 16;
}
__device__ __forceinline__ uint32_t pack2(float lo, float hi) {
    return f2b(lo) | (f2b(hi) << 16);
}

// ---------------- packed: prep (x->bf16, weights->bf16) + edge bucketing ---
__global__ __launch_bounds__(256) void pb_k(const float* __restrict__ x,
                       const float* __restrict__ Wl0, const float* __restrict__ Wr0,
                       const float* __restrict__ Wl1, const float* __restrict__ Wr1,
                       const float* __restrict__ Wl2, const float* __restrict__ Wr2,
                       uint32_t* __restrict__ X0, uint32_t* __restrict__ Wc,
                       const int* __restrict__ src, const int* __restrict__ dst,
                       int* __restrict__ bcnt, uint2* __restrict__ ebuf)
{
    const int t = threadIdx.x;
    if (blockIdx.x < 512) {
        __shared__ int h[256], base[256], cur[256];
        h[t] = 0; cur[t] = 0;
        __syncthreads();
        const int chunk = (N_EDGES + 511) / 512;
        const int e0 = blockIdx.x * chunk;
        int e1 = e0 + chunk; if (e1 > N_EDGES) e1 = N_EDGES;
        for (int e = e0 + t; e < e1; e += 256) {
            int b = dst[e] >> 8;
            atomicAdd(&h[b], 1);
        }
        __syncthreads();
        if (t < NBUCK) base[t] = (h[t] > 0) ? atomicAdd(&bcnt[t], h[t]) : 0;
        __syncthreads();
        for (int e = e0 + t; e < e1; e += 256) {
            int s = src[e], d = dst[e];
            int b = d >> 8;
            int r = atomicAdd(&cur[b], 1);
            int pos = base[b] + r;
            if (pos < CAP) ebuf[b * CAP + pos] = make_uint2((uint32_t)s, (uint32_t)d);
        }
    } else {
        const int NX = N_NODES * D / 2;      // 3,200,000 uints
        const int NW = 3 * 128 * 128;        // 49,152 uints
        const int bid = blockIdx.x - 512;    // 0..2047
        for (int i = bid * 256 + t; i < NX + NW; i += 2048 * 256) {
            if (i < NX) {
                const float2 v = reinterpret_cast<const float2*>(x)[i];
                X0[i] = pack2(v.x, v.y);
            } else {
                int j = i - NX;
                int l = j / 16384;
                int r = j % 16384;
                int n = r >> 7;
                int k2 = (r & 127) * 2;
                const float* Wl = (l == 0) ? Wl0 : (l == 1) ? Wl1 : Wl2;
                const float* Wr = (l == 0) ? Wr0 : (l == 1) ? Wr1 : Wr2;
                float a, b;
                if (k2 < 128) { a = Wl[n * 128 + k2];       b = Wl[n * 128 + k2 + 1]; }
                else          { a = Wr[n * 128 + k2 - 128]; b = Wr[n * 128 + k2 - 127]; }
                Wc[j] = pack2(a, b);
            }
        }
    }
}

// ---------------- CSR: one block per bucket, self-scans bucket counts ------
__global__ __launch_bounds__(256) void csr_k(const uint2* __restrict__ ebuf,
                                             const int* __restrict__ bcnt,
                                             int* __restrict__ rowptr,
                                             int* __restrict__ adj)
{
    __shared__ int bs[256], cntL[256], offL[256], curL[256];
    const int b = blockIdx.x;
    const int t = threadIdx.x;
    const int n0 = b << 8;
    int bv = (t < NBUCK) ? bcnt[t] : 0;
    bs[t] = bv;
    __syncthreads();
    for (int d = 1; d < 256; d <<= 1) {
        int tmp = (t >= d) ? bs[t - d] : 0;
        __syncthreads();
        bs[t] += tmp;
        __syncthreads();
    }
    const int gbase = (b == 0) ? 0 : bs[b - 1];
    const int m = bcnt[b];
    cntL[t] = 0; curL[t] = 0;
    __syncthreads();
    const uint2* eb = ebuf + b * CAP;
    for (int i = t; i < m; i += 256)
        atomicAdd(&cntL[(int)eb[i].y - n0], 1);
    __syncthreads();
    int v = cntL[t];
    offL[t] = v;
    __syncthreads();
    for (int d = 1; d < 256; d <<= 1) {
        int tmp = (t >= d) ? offL[t - d] : 0;
        __syncthreads();
        offL[t] += tmp;
        __syncthreads();
    }
    int excl = offL[t] - v;
    int node = n0 + t;
    if (node < N_NODES) rowptr[node] = gbase + excl;
    if (b == NBUCK - 1 && t == 0) rowptr[N_NODES] = N_EDGES;
    __syncthreads();
    offL[t] = excl;
    __syncthreads();
    for (int i = t; i < m; i += 256) {
        uint2 e = eb[i];
        int d = (int)e.y - n0;
        int r = atomicAdd(&curL[d], 1);
        adj[gbase + offL[d] + r] = (int)e.x;
    }
}

// ---------------- fused layer: mean-agg (into LDS) + GEMM -----------------
// Block = 256 thr (4 waves), 16 output rows, grid 3125 (= 50000/16, exact).
// Phase 1: wave w aggregates 4 nodes (w*4+i) -> bf16 means in swizzled LDS.
// Phase 2: waves split the 128 cols (32 each); A = 16-row LDS tile (means)
// + global self rows; B from global (L2-resident 64 KB).
// LAYER 0: +relu, bf16 out. LAYER 1: bf16 out + BN col-stats -> colsums.
// LAYER 2: BN+relu applied to G2 on the fly (gather + self path); fp32 out.
__device__ __forceinline__ s16x8 bn8(uint4 u, const float* bnS, int cb) {
    uint32_t uu[4] = {u.x, u.y, u.z, u.w};
    uint32_t w[4];
#pragma unroll
    for (int i = 0; i < 4; ++i) {
        int c = cb + 2 * i;
        float lo = fmaxf(fmaf(bflo(uu[i]), bnS[c],     bnS[128 + c]),     0.f);
        float hi = fmaxf(fmaf(bfhi(uu[i]), bnS[c + 1], bnS[128 + c + 1]), 0.f);
        w[i] = pack2(lo, hi);
    }
    uint4 r = make_uint4(w[0], w[1], w[2], w[3]);
    return __builtin_bit_cast(s16x8, r);
}

template <int LAYER>
__global__ __launch_bounds__(256) void fused_k(const uint32_t* __restrict__ inB,
                                               const int* __restrict__ rowptr,
                                               const int* __restrict__ adj,
                                               const uint32_t* __restrict__ Wc,
                                               const float* __restrict__ bias,
                                               void* __restrict__ outp,
                                               float* __restrict__ colsums,
                                               const float* __restrict__ gamma,
                                               const float* __restrict__ beta)
{
    __shared__ uint32_t meanS[1024];   // 16 rows x 128 bf16, XOR-swizzled
    __shared__ float extraS[256];      // L1: col {sum,sumsq}; L2: BN {sc,sh}
    const int t = threadIdx.x;
    const int lane = t & 63;
    const int wid = t >> 6;
    const int blockBase = blockIdx.x * 16;

    if constexpr (LAYER == 1) extraS[t] = 0.f;
    if constexpr (LAYER == 2) {
        if (t < 128) {
            float mu  = colsums[t] * (1.0f / N_NODES);
            float var = colsums[128 + t] * (1.0f / N_NODES) - mu * mu;
            float sc  = gamma[t] * rsqrtf(var + 1e-5f);
            extraS[t] = sc;
            extraS[128 + t] = beta[t] - mu * sc;
        }
    }
    __syncthreads();

    // ---- phase 1: each wave aggregates 4 nodes ----
    const int sub = lane >> 4;     // 0..3
    const int col4 = lane & 15;    // 16B chunk within row
    float vsc[8], vsh[8];
    if constexpr (LAYER == 2) {
#pragma unroll
        for (int k = 0; k < 8; ++k) {
            int c = col4 * 8 + k;
            vsc[k] = extraS[c]; vsh[k] = extraS[128 + c];
        }
    }
#pragma unroll
    for (int i = 0; i < 4; ++i) {
        const int rl = wid * 4 + i;           // local row 0..15
        const int ni = blockBase + rl;        // grid exact: always < N_NODES
        const int start = rowptr[ni], end = rowptr[ni + 1];
        float acc[8];
#pragma unroll
        for (int k = 0; k < 8; ++k) acc[k] = 0.f;
        for (int base = start; base < end; base += 64) {
            int cnt = end - base;
            if (cnt > 64) cnt = 64;
            int idx = (base + lane < end) ? adj[base + lane] : 0;
            for (int j = 0; j < cnt; j += 8) {
                int e0 = j + sub;
                int e1 = j + 4 + sub;
                int s0 = __shfl(idx, e0, 64);
                int s1 = __shfl(idx, e1, 64);
                bool v0 = e0 < cnt;
                bool v1 = e1 < cnt;
                uint4 a = *reinterpret_cast<const uint4*>(inB + (v0 ? s0 : 0) * 64 + col4 * 4);
                uint4 b = *reinterpret_cast<const uint4*>(inB + (v1 ? s1 : 0) * 64 + col4 * 4);
                if constexpr (LAYER == 2) {
                    float m0 = v0 ? 1.f : 0.f;
                    float m1 = v1 ? 1.f : 0.f;
#define ACCBN(K, GA, GB) acc[K] += m0 * fmaxf(fmaf((GA), vsc[K], vsh[K]), 0.f) \
                                 + m1 * fmaxf(fmaf((GB), vsc[K], vsh[K]), 0.f)
                    ACCBN(0, bflo(a.x), bflo(b.x)); ACCBN(1, bfhi(a.x), bfhi(b.x));
                    ACCBN(2, bflo(a.y), bflo(b.y)); ACCBN(3, bfhi(a.y), bfhi(b.y));
                    ACCBN(4, bflo(a.z), bflo(b.z)); ACCBN(5, bfhi(a.z), bfhi(b.z));
                    ACCBN(6, bflo(a.w), bflo(b.w)); ACCBN(7, bfhi(a.w), bfhi(b.w));
#undef ACCBN
                } else {
                    if (!v0) a = make_uint4(0, 0, 0, 0);
                    if (!v1) b = make_uint4(0, 0, 0, 0);
                    acc[0] += bflo(a.x); acc[1] += bfhi(a.x);
                    acc[2] += bflo(a.y); acc[3] += bfhi(a.y);
                    acc[4] += bflo(a.z); acc[5] += bfhi(a.z);
                    acc[6] += bflo(a.w); acc[7] += bfhi(a.w);
                    acc[0] += bflo(b.x); acc[1] += bfhi(b.x);
                    acc[2] += bflo(b.y); acc[3] += bfhi(b.y);
                    acc[4] += bflo(b.z); acc[5] += bfhi(b.z);
                    acc[6] += bflo(b.w); acc[7] += bfhi(b.w);
                }
            }
        }
#pragma unroll
        for (int k = 0; k < 8; ++k) {
            acc[k] += __shfl_xor(acc[k], 16, 64);
            acc[k] += __shfl_xor(acc[k], 32, 64);
        }
        if (sub == 0) {
            int deg = end - start;
            float sc = 1.0f / (float)(deg > 0 ? deg : 1);
            uint4 w;
            w.x = pack2(acc[0] * sc, acc[1] * sc);
            w.y = pack2(acc[2] * sc, acc[3] * sc);
            w.z = pack2(acc[4] * sc, acc[5] * sc);
            w.w = pack2(acc[6] * sc, acc[7] * sc);
            const int off = (col4 * 4) ^ ((rl & 7) << 2);
            *reinterpret_cast<uint4*>(meanS + rl * 64 + off) = w;
        }
    }
    __syncthreads();

    // ---- phase 2: MFMA; wave w covers cols [w*32, w*32+32) of 16 rows ----
    const int l15 = lane & 15;
    const int kc = lane >> 4;
    const int rl0 = l15;                      // LDS row for A
    const int m0 = blockBase + l15;           // global self row (always valid)
    const uint32_t* Wg = Wc + LAYER * 16384;

    f32x4 acc[2];
    acc[0] = (f32x4){0.f, 0.f, 0.f, 0.f};
    acc[1] = (f32x4){0.f, 0.f, 0.f, 0.f};

#pragma unroll
    for (int ks = 0; ks < 8; ++ks) {
        const int koff = (ks & 3) * 16 + kc * 4;
        s16x8 a0;
        if (ks < 4) {
            a0 = *reinterpret_cast<const s16x8*>(meanS + rl0 * 64 + (koff ^ ((rl0 & 7) << 2)));
        } else {
            if constexpr (LAYER == 2) {
                const int cb = (ks & 3) * 32 + kc * 8;
                uint4 u0 = *reinterpret_cast<const uint4*>(inB + m0 * 64 + koff);
                a0 = bn8(u0, extraS, cb);
            } else {
                a0 = *reinterpret_cast<const s16x8*>(inB + m0 * 64 + koff);
            }
        }
#pragma unroll
        for (int nf = 0; nf < 2; ++nf) {
            const int col = wid * 32 + nf * 16 + l15;
            s16x8 b = *reinterpret_cast<const s16x8*>(Wg + col * 128 + ks * 16 + kc * 4);
            acc[nf] = __builtin_amdgcn_mfma_f32_16x16x32_bf16(a0, b, acc[nf], 0, 0, 0);
        }
    }

    const int rb = blockBase + kc * 4;
#pragma unroll
    for (int nf = 0; nf < 2; ++nf) {
        int col = wid * 32 + nf * 16 + l15;
        float bia = bias[col];
        float s = 0.f, q = 0.f;
#pragma unroll
        for (int r = 0; r < 4; ++r) {
            int row = rb + r;
            float v = acc[nf][r] + bia;
            if (LAYER == 0) v = v > 0.f ? v : 0.f;
            if (LAYER == 2)
                ((float*)outp)[row * 128 + col] = v;
            else
                ((unsigned short*)outp)[row * 128 + col] = (unsigned short)f2b(v);
            if constexpr (LAYER == 1) { s += v; q += v * v; }
        }
        if constexpr (LAYER == 1) {
            atomicAdd(&extraS[col], s);
            atomicAdd(&extraS[128 + col], q);
        }
    }
    if constexpr (LAYER == 1) {
        __syncthreads();
        if (t < 128) {
            atomicAdd(&colsums[t], extraS[t]);
            atomicAdd(&colsums[128 + t], extraS[128 + t]);
        }
    }
}

// ---------------- launch ---------------------------------------------------
// Workspace (~49.2 MB):
//   bcnt    @ 0          (784, pad 1024)   [zeroed]
//   colsums @ 1024       (1024)            [zeroed]
//   rowptr  @ 4096       (200,004)
//   adj     @ 204,160    (3,200,000)
//   ebuf    @ 3,404,160  (7,225,344 = 196*4608*8)
//   bufA    @ 10,629,504 (12.8 MB)  X0, later G2
//   bufC    @ 36,229,504 (12.8 MB)  G1
//   Wc      @ 49,029,504 (196,608)
extern "C" void kernel_launch(void* const* d_in, const int* in_sizes, int n_in,
                              void* d_out, int out_size, void* d_ws, size_t ws_size,
                              hipStream_t stream)
{
    const float* x      = (const float*)d_in[0];
    const int*   ei     = (const int*)d_in[1];
    const float* Wl0    = (const float*)d_in[2];
    const float* bl0    = (const float*)d_in[3];
    const float* Wr0    = (const float*)d_in[4];
    const float* Wl1    = (const float*)d_in[5];
    const float* bl1    = (const float*)d_in[6];
    const float* Wr1    = (const float*)d_in[7];
    const float* Wl2    = (const float*)d_in[8];
    const float* bl2    = (const float*)d_in[9];
    const float* Wr2    = (const float*)d_in[10];
    const float* gamma1 = (const float*)d_in[11];
    const float* beta1  = (const float*)d_in[12];

    char* ws = (char*)d_ws;
    int*      bcnt    = (int*)(ws + 0);
    float*    colsums = (float*)(ws + 1024);
    int*      rowptr  = (int*)(ws + 4096);
    int*      adj     = (int*)(ws + 204160);
    uint2*    ebuf    = (uint2*)(ws + 3404160);
    uint32_t* bufA    = (uint32_t*)(ws + 10629504);
    uint32_t* bufC    = (uint32_t*)(ws + 36229504);
    uint32_t* Wc      = (uint32_t*)(ws + 49029504);
    // liveness-based aliases
    uint32_t* X0 = bufA;   // dead after fused<0>
    uint32_t* G1 = bufC;   // dead after fused<1>
    uint32_t* G2 = bufA;

    const int* srcI = ei;
    const int* dstI = ei + N_EDGES;

    hipMemsetAsync(ws, 0, 2048, stream);   // bcnt + colsums
    pb_k<<<2560, 256, 0, stream>>>(x, Wl0, Wr0, Wl1, Wr1, Wl2, Wr2, X0, Wc,
                                   srcI, dstI, bcnt, ebuf);
    csr_k<<<NBUCK, 256, 0, stream>>>(ebuf, bcnt, rowptr, adj);

    const int NBLK = N_NODES / 16;   // 3125, exact
    fused_k<0><<<NBLK, 256, 0, stream>>>(X0, rowptr, adj, Wc, bl0, (void*)G1,
                                         nullptr, nullptr, nullptr);
    fused_k<1><<<NBLK, 256, 0, stream>>>(G1, rowptr, adj, Wc, bl1, (void*)G2,
                                         colsums, nullptr, nullptr);
    fused_k<2><<<NBLK, 256, 0, stream>>>(G2, rowptr, adj, Wc, bl2, d_out,
                                         colsums, gamma1, beta1);
}